// Round 3
// baseline (62.935 us; speedup 1.0000x reference)
//
#include <hip/hip_runtime.h>
#include <math.h>

// Problem constants (reference: POS_LEN=32, NUM_F=16, HIDDEN=256, T=32)
#define NUM_F   16
#define FIN     (8 * NUM_F)      // 128 fourier features
#define HIDDEN  256
#define TOUT    32
#define NOFF    63               // distinct offset values: -31..31
#define NPAIRS_TBL (NOFF * NOFF) // 3969
#define PPB1    8                // pairs per block, hidden kernel
#define PPB2    8                // pairs per block, out kernel
#define NBLK    ((NPAIRS_TBL + PPB1 - 1) / PPB1)  // 497

// ---------------------------------------------------------------------------
// K0: fourier features -> global. feats[pair][f], f = g*16+k,
// g: 0 sin(a) 1 cos(a) 2 sin(b) 3 cos(b) 4 sin(p) 5 cos(p) 6 sin(m) 7 cos(m)
__global__ __launch_bounds__(256) void gab_feats_kernel(
    const float* __restrict__ freqs, float* __restrict__ feats)
{
    const int e = blockIdx.x * 256 + threadIdx.x;
    if (e >= NPAIRS_TBL * FIN) return;
    const int pair = e >> 7;
    const int f    = e & 127;
    const int g    = f >> 4;
    const float fr = freqs[f & 15];
    const float dr = (float)(pair / NOFF - (NOFF / 2));
    const float dc = (float)(pair % NOFF - (NOFF / 2));
    float base;
    switch (g >> 1) {
        case 0:  base = dr;      break;
        case 1:  base = dc;      break;
        case 2:  base = dr + dc; break;
        default: base = dr - dc; break;
    }
    const float arg = base * fr;
    feats[e] = (g & 1) ? cosf(arg) : sinf(arg);
}

// ---------------------------------------------------------------------------
// K1: H[pair][t] = silu(W1[t,:] . feats[pair,:] + b1[t]).
// Thread t owns hidden unit t; W1 row staged once in 32 float4 VGPRs.
// feats read at a block-uniform address -> s_load broadcast (SGPR operand),
// no LDS, no barriers.
__global__ __launch_bounds__(256) void gab_hidden_kernel(
    const float* __restrict__ feats,
    const float* __restrict__ W1, const float* __restrict__ b1,
    float* __restrict__ H)
{
    const int t = threadIdx.x;
    float4 w1r[32];
    {
        const float4* w1v = (const float4*)(W1 + t * FIN);
        #pragma unroll
        for (int k = 0; k < 32; ++k) w1r[k] = w1v[k];
    }
    const float b1t = b1[t];

    for (int pp = 0; pp < PPB1; ++pp) {
        const int pair = blockIdx.x * PPB1 + pp;   // block-uniform
        if (pair >= NPAIRS_TBL) return;            // no barriers: plain return ok
        const float4* __restrict__ fr = (const float4*)(feats + pair * FIN);
        float a0 = 0.f, a1 = 0.f, a2 = 0.f, a3 = 0.f;
        #pragma unroll
        for (int k = 0; k < 32; k += 2) {
            const float4 fa = fr[k], fb = fr[k + 1];
            a0 = fmaf(w1r[k].x,     fa.x, a0); a1 = fmaf(w1r[k].y,     fa.y, a1);
            a2 = fmaf(w1r[k].z,     fa.z, a2); a3 = fmaf(w1r[k].w,     fa.w, a3);
            a0 = fmaf(w1r[k + 1].x, fb.x, a0); a1 = fmaf(w1r[k + 1].y, fb.y, a1);
            a2 = fmaf(w1r[k + 1].z, fb.z, a2); a3 = fmaf(w1r[k + 1].w, fb.w, a3);
        }
        const float pre = (a0 + a1) + (a2 + a3) + b1t;
        H[pair * HIDDEN + t] = pre / (1.0f + expf(-pre));  // SiLU
    }
}

// ---------------------------------------------------------------------------
// K2: table[pair][o] = (W2[o,:] . H[pair,:] + b2[o]) / sqrt(T).
// Thread (o = t&31, c = t>>5) dots 32 elements; W2 chunk in 8 float4 VGPRs.
// shfl_xor(32) merges the wave's two c-chunks; LDS part[] merges waves.
__global__ __launch_bounds__(256) void gab_out_kernel(
    const float* __restrict__ H,
    const float* __restrict__ W2, const float* __restrict__ b2,
    float* __restrict__ table)
{
    __shared__ float part[2][4][33];
    const int t = threadIdx.x;
    const int o = t & 31;
    const int c = t >> 5;

    float4 w2r[8];
    {
        const float4* w2v = (const float4*)(W2 + o * HIDDEN + c * 32);
        #pragma unroll
        for (int k = 0; k < 8; ++k) w2r[k] = w2v[k];
    }
    const float b2o = b2[o];

    for (int pp = 0; pp < PPB2; ++pp) {
        const int pair = blockIdx.x * PPB2 + pp;   // block-uniform
        if (pair >= NPAIRS_TBL) break;             // uniform break, barrier-safe
        const float4* h4 = (const float4*)(H + pair * HIDDEN + c * 32);
        float s0 = 0.f, s1 = 0.f, s2 = 0.f, s3 = 0.f;
        #pragma unroll
        for (int k = 0; k < 8; k += 2) {
            const float4 ha = h4[k], hb = h4[k + 1];
            s0 = fmaf(w2r[k].x,     ha.x, s0); s1 = fmaf(w2r[k].y,     ha.y, s1);
            s2 = fmaf(w2r[k].z,     ha.z, s2); s3 = fmaf(w2r[k].w,     ha.w, s3);
            s0 = fmaf(w2r[k + 1].x, hb.x, s0); s1 = fmaf(w2r[k + 1].y, hb.y, s1);
            s2 = fmaf(w2r[k + 1].z, hb.z, s2); s3 = fmaf(w2r[k + 1].w, hb.w, s3);
        }
        float s = (s0 + s1) + (s2 + s3);
        s += __shfl_xor(s, 32);
        if ((t & 63) < 32) part[pp & 1][t >> 6][o] = s;
        __syncthreads();
        if (t < TOUT) {
            const float r = part[pp & 1][0][t] + part[pp & 1][1][t]
                          + part[pp & 1][2][t] + part[pp & 1][3][t] + b2o;
            table[pair * TOUT + t] = r * 0.17677669529663687f; // * 1/sqrt(32)
        }
    }
}

// ---------------------------------------------------------------------------
// Fallback single-kernel table (R2 version) when ws_size is too small for
// the staged pipeline.
__global__ __launch_bounds__(256, 2) void gab_table_kernel(
    const float* __restrict__ freqs,
    const float* __restrict__ W1, const float* __restrict__ b1,
    const float* __restrict__ W2, const float* __restrict__ b2,
    float* __restrict__ table)
{
    __shared__ float feats[FIN];
    __shared__ float hbuf[HIDDEN];
    __shared__ float part[4][33];

    const int t = threadIdx.x;
    const int o = t & 31;
    const int c = t >> 5;

    float4 w1r[32];
    {
        const float4* w1v = (const float4*)(W1 + t * FIN);
        #pragma unroll
        for (int k = 0; k < 32; ++k) w1r[k] = w1v[k];
    }
    float4 w2r[8];
    {
        const float4* w2v = (const float4*)(W2 + o * HIDDEN + c * 32);
        #pragma unroll
        for (int k = 0; k < 8; ++k) w2r[k] = w2v[k];
    }
    const float b1t = b1[t];
    const float b2o = b2[o];
    const float myfreq = (t < FIN) ? freqs[t & 15] : 0.0f;

    for (int pp = 0; pp < PPB1; ++pp) {
        const int pair = blockIdx.x * PPB1 + pp;
        if (pair >= NPAIRS_TBL) break;
        const float dr = (float)(pair / NOFF - (NOFF / 2));
        const float dc = (float)(pair % NOFF - (NOFF / 2));

        if (t < FIN) {
            const int g = t >> 4;
            float base;
            switch (g >> 1) {
                case 0:  base = dr;      break;
                case 1:  base = dc;      break;
                case 2:  base = dr + dc; break;
                default: base = dr - dc; break;
            }
            const float arg = base * myfreq;
            feats[t] = (g & 1) ? cosf(arg) : sinf(arg);
        }
        __syncthreads();

        float a0 = 0.f, a1 = 0.f, a2 = 0.f, a3 = 0.f;
        const float4* f4 = (const float4*)feats;
        #pragma unroll
        for (int k = 0; k < 32; k += 2) {
            float4 fa = f4[k], fb = f4[k + 1];
            a0 = fmaf(w1r[k].x,     fa.x, a0); a1 = fmaf(w1r[k].y,     fa.y, a1);
            a2 = fmaf(w1r[k].z,     fa.z, a2); a3 = fmaf(w1r[k].w,     fa.w, a3);
            a0 = fmaf(w1r[k + 1].x, fb.x, a0); a1 = fmaf(w1r[k + 1].y, fb.y, a1);
            a2 = fmaf(w1r[k + 1].z, fb.z, a2); a3 = fmaf(w1r[k + 1].w, fb.w, a3);
        }
        const float pre = (a0 + a1) + (a2 + a3) + b1t;
        hbuf[t] = pre / (1.0f + expf(-pre));
        __syncthreads();

        float s0 = 0.f, s1 = 0.f, s2 = 0.f, s3 = 0.f;
        const float4* h4 = (const float4*)(hbuf + c * 32);
        #pragma unroll
        for (int k = 0; k < 8; k += 2) {
            float4 ha = h4[k], hb = h4[k + 1];
            s0 = fmaf(w2r[k].x,     ha.x, s0); s1 = fmaf(w2r[k].y,     ha.y, s1);
            s2 = fmaf(w2r[k].z,     ha.z, s2); s3 = fmaf(w2r[k].w,     ha.w, s3);
            s0 = fmaf(w2r[k + 1].x, hb.x, s0); s1 = fmaf(w2r[k + 1].y, hb.y, s1);
            s2 = fmaf(w2r[k + 1].z, hb.z, s2); s3 = fmaf(w2r[k + 1].w, hb.w, s3);
        }
        float s = (s0 + s1) + (s2 + s3);
        s += __shfl_xor(s, 32);
        if ((t & 63) < 32) part[t >> 6][o] = s;
        __syncthreads();
        if (t < TOUT) {
            const float r = part[0][t] + part[1][t] + part[2][t] + part[3][t] + b2o;
            table[pair * TOUT + t] = r * 0.17677669529663687f;
        }
        __syncthreads();
    }
}

// ---------------------------------------------------------------------------
// Gather: dr/dc derived exactly from the flat index. Only HBM traffic is the
// 128 MiB coalesced float4 output stream; table stays L2-resident.
__global__ __launch_bounds__(256) void gab_gather_kernel(
    const float* __restrict__ table,
    float4* __restrict__ out, int npairs)
{
    const int total = npairs * 8;
    const int stride = gridDim.x * blockDim.x;
    const float4* __restrict__ tbl4 = (const float4*)table;

    for (int idx = blockIdx.x * blockDim.x + threadIdx.x; idx < total; idx += stride) {
        const int p = idx >> 3;
        const int l = idx & 7;
        const int i = p >> 10;
        const int j = p & 1023;
        const int ir = (i >> 5) - (j >> 5) + (NOFF / 2);
        const int ic = (i & 31) - (j & 31) + (NOFF / 2);
        out[idx] = tbl4[(ir * NOFF + ic) * (TOUT / 4) + l];
    }
}

// ---------------------------------------------------------------------------
extern "C" void kernel_launch(void* const* d_in, const int* in_sizes, int n_in,
                              void* d_out, int out_size, void* d_ws, size_t ws_size,
                              hipStream_t stream) {
    // inputs: 0 seq_len 1 freqs(16) 2 W1(256*128) 3 b1(256) 4 W2(32*256)
    //         5 b2(32) 6 dr(S*S) 7 dc(S*S)
    const float* freqs = (const float*)d_in[1];
    const float* W1    = (const float*)d_in[2];
    const float* b1    = (const float*)d_in[3];
    const float* W2    = (const float*)d_in[4];
    const float* b2    = (const float*)d_in[5];
    float* out = (float*)d_out;

    const int npairs = in_sizes[6];                // S*S = 1024*1024

    // ws layout: [table 508 KB][feats 2 MB][H 4 MB]
    const size_t TBL_B   = (size_t)NPAIRS_TBL * TOUT * 4;    // 508,032 B
    const size_t FEATS_B = (size_t)NPAIRS_TBL * FIN * 4;     // 2,032,128 B
    const size_t H_B     = (size_t)NPAIRS_TBL * HIDDEN * 4;  // 4,064,256 B
    float* table = (float*)d_ws;

    if (ws_size >= TBL_B + FEATS_B + H_B) {
        float* feats = (float*)((char*)d_ws + TBL_B);
        float* H     = (float*)((char*)d_ws + TBL_B + FEATS_B);
        const int e_total = NPAIRS_TBL * FIN;
        gab_feats_kernel <<<(e_total + 255) / 256, 256, 0, stream>>>(freqs, feats);
        gab_hidden_kernel<<<NBLK, 256, 0, stream>>>(feats, W1, b1, H);
        gab_out_kernel   <<<NBLK, 256, 0, stream>>>(H, W2, b2, table);
    } else {
        gab_table_kernel <<<NBLK, 256, 0, stream>>>(freqs, W1, b1, W2, b2, table);
    }

    gab_gather_kernel<<<2048, 256, 0, stream>>>(table, (float4*)out, npairs);
}

// Round 4
// 56.143 us; speedup vs baseline: 1.1210x; 1.1210x over previous
//
#include <hip/hip_runtime.h>
#include <math.h>

// Problem constants (reference: POS_LEN=32, NUM_F=16, HIDDEN=256, T=32)
#define NUM_F   16
#define FIN     (8 * NUM_F)      // 128 fourier features
#define HIDDEN  256
#define TOUT    32
#define NOFF    63               // distinct offset values: -31..31
#define NPAIRS_TBL (NOFF * NOFF) // 3969
#define PPB     8                // pairs per block (table kernel)
#define NBLK    ((NPAIRS_TBL + PPB - 1) / PPB)   // 497

// ---------------------------------------------------------------------------
// K0: fourier features -> global scratch. feats[pair][f], f = g*16+k.
// ~0.5M elements, trivial.
__global__ __launch_bounds__(256) void gab_feats_kernel(
    const float* __restrict__ freqs, float* __restrict__ feats)
{
    const int e = blockIdx.x * 256 + threadIdx.x;
    if (e >= NPAIRS_TBL * FIN) return;
    const int pair = e >> 7;
    const int f    = e & 127;
    const int g    = f >> 4;
    const float fr = freqs[f & 15];
    const float dr = (float)(pair / NOFF - (NOFF / 2));
    const float dc = (float)(pair % NOFF - (NOFF / 2));
    float base;
    switch (g >> 1) {
        case 0:  base = dr;      break;
        case 1:  base = dc;      break;
        case 2:  base = dr + dc; break;
        default: base = dr - dc; break;
    }
    const float arg = base * fr;
    feats[e] = (g & 1) ? cosf(arg) : sinf(arg);
}

// ---------------------------------------------------------------------------
// K1: fused hidden+out. Thread t = hidden unit t, W1 row in 32 float4 VGPRs.
// feats read from GLOBAL at a block-uniform address: one 16B line per load
// instruction, L1-broadcast to all 64 lanes — no LDS pipe, no per-wave
// redundancy. H stays in LDS (written once, read 8 b128/thread). Layer-2
// merged via shfl_xor(32) + double-buffered part[] (2 barriers/pair).
__global__ __launch_bounds__(256) void gab_mlp_kernel(
    const float* __restrict__ feats,
    const float* __restrict__ W1, const float* __restrict__ b1,
    const float* __restrict__ W2, const float* __restrict__ b2,
    float* __restrict__ table)
{
    __shared__ float hbuf[HIDDEN];
    __shared__ float part[2][4][33];

    const int t = threadIdx.x;
    const int o = t & 31;               // output unit
    const int c = t >> 5;               // k-chunk of the dot-256

    float4 w1r[32];                     // W1 row t (128 floats, 128 VGPRs)
    {
        const float4* w1v = (const float4*)(W1 + t * FIN);
        #pragma unroll
        for (int k = 0; k < 32; ++k) w1r[k] = w1v[k];
    }
    float4 w2r[8];                      // W2[o][c*32 .. c*32+31]
    {
        const float4* w2v = (const float4*)(W2 + o * HIDDEN + c * 32);
        #pragma unroll
        for (int k = 0; k < 8; ++k) w2r[k] = w2v[k];
    }
    const float b1t = b1[t];
    const float b2o = b2[o];

    for (int pp = 0; pp < PPB; ++pp) {
        const int pair = blockIdx.x * PPB + pp;   // block-uniform
        if (pair >= NPAIRS_TBL) break;            // uniform break, barrier-safe

        // layer 1: feats via uniform global loads (L1 broadcast)
        const float4* __restrict__ fr = (const float4*)(feats + pair * FIN);
        float a0 = 0.f, a1 = 0.f, a2 = 0.f, a3 = 0.f;
        #pragma unroll
        for (int k = 0; k < 32; k += 2) {
            const float4 fa = fr[k], fb = fr[k + 1];
            a0 = fmaf(w1r[k].x,     fa.x, a0); a1 = fmaf(w1r[k].y,     fa.y, a1);
            a2 = fmaf(w1r[k].z,     fa.z, a2); a3 = fmaf(w1r[k].w,     fa.w, a3);
            a0 = fmaf(w1r[k + 1].x, fb.x, a0); a1 = fmaf(w1r[k + 1].y, fb.y, a1);
            a2 = fmaf(w1r[k + 1].z, fb.z, a2); a3 = fmaf(w1r[k + 1].w, fb.w, a3);
        }
        const float pre = (a0 + a1) + (a2 + a3) + b1t;
        hbuf[t] = pre / (1.0f + expf(-pre));      // SiLU
        __syncthreads();                          // hbuf write -> read

        // layer 2: thread (o,c) dots 32 of 256
        const float4* h4 = (const float4*)(hbuf + c * 32);
        float s0 = 0.f, s1 = 0.f, s2 = 0.f, s3 = 0.f;
        #pragma unroll
        for (int k = 0; k < 8; k += 2) {
            const float4 ha = h4[k], hb = h4[k + 1];
            s0 = fmaf(w2r[k].x,     ha.x, s0); s1 = fmaf(w2r[k].y,     ha.y, s1);
            s2 = fmaf(w2r[k].z,     ha.z, s2); s3 = fmaf(w2r[k].w,     ha.w, s3);
            s0 = fmaf(w2r[k + 1].x, hb.x, s0); s1 = fmaf(w2r[k + 1].y, hb.y, s1);
            s2 = fmaf(w2r[k + 1].z, hb.z, s2); s3 = fmaf(w2r[k + 1].w, hb.w, s3);
        }
        float s = (s0 + s1) + (s2 + s3);
        s += __shfl_xor(s, 32);                   // merge the wave's 2 c-chunks
        if ((t & 63) < 32) part[pp & 1][t >> 6][o] = s;
        __syncthreads();                          // part write -> read
                                                  // (also covers hbuf WAR:
                                                  //  double-buffered part,
                                                  //  hbuf rewritten only after
                                                  //  this barrier)
        if (t < TOUT) {
            const float r = part[pp & 1][0][t] + part[pp & 1][1][t]
                          + part[pp & 1][2][t] + part[pp & 1][3][t] + b2o;
            table[pair * TOUT + t] = r * 0.17677669529663687f; // * 1/sqrt(32)
        }
    }
}

// ---------------------------------------------------------------------------
// Fallback: R2's fully-fused table kernel (used only if ws too small).
__global__ __launch_bounds__(256, 2) void gab_table_kernel(
    const float* __restrict__ freqs,
    const float* __restrict__ W1, const float* __restrict__ b1,
    const float* __restrict__ W2, const float* __restrict__ b2,
    float* __restrict__ table)
{
    __shared__ float feats[FIN];
    __shared__ float hbuf[HIDDEN];
    __shared__ float part[4][33];

    const int t = threadIdx.x;
    const int o = t & 31;
    const int c = t >> 5;

    float4 w1r[32];
    {
        const float4* w1v = (const float4*)(W1 + t * FIN);
        #pragma unroll
        for (int k = 0; k < 32; ++k) w1r[k] = w1v[k];
    }
    float4 w2r[8];
    {
        const float4* w2v = (const float4*)(W2 + o * HIDDEN + c * 32);
        #pragma unroll
        for (int k = 0; k < 8; ++k) w2r[k] = w2v[k];
    }
    const float b1t = b1[t];
    const float b2o = b2[o];
    const float myfreq = (t < FIN) ? freqs[t & 15] : 0.0f;

    for (int pp = 0; pp < PPB; ++pp) {
        const int pair = blockIdx.x * PPB + pp;
        if (pair >= NPAIRS_TBL) break;
        const float dr = (float)(pair / NOFF - (NOFF / 2));
        const float dc = (float)(pair % NOFF - (NOFF / 2));

        if (t < FIN) {
            const int g = t >> 4;
            float base;
            switch (g >> 1) {
                case 0:  base = dr;      break;
                case 1:  base = dc;      break;
                case 2:  base = dr + dc; break;
                default: base = dr - dc; break;
            }
            const float arg = base * myfreq;
            feats[t] = (g & 1) ? cosf(arg) : sinf(arg);
        }
        __syncthreads();

        float a0 = 0.f, a1 = 0.f, a2 = 0.f, a3 = 0.f;
        const float4* f4 = (const float4*)feats;
        #pragma unroll
        for (int k = 0; k < 32; k += 2) {
            float4 fa = f4[k], fb = f4[k + 1];
            a0 = fmaf(w1r[k].x,     fa.x, a0); a1 = fmaf(w1r[k].y,     fa.y, a1);
            a2 = fmaf(w1r[k].z,     fa.z, a2); a3 = fmaf(w1r[k].w,     fa.w, a3);
            a0 = fmaf(w1r[k + 1].x, fb.x, a0); a1 = fmaf(w1r[k + 1].y, fb.y, a1);
            a2 = fmaf(w1r[k + 1].z, fb.z, a2); a3 = fmaf(w1r[k + 1].w, fb.w, a3);
        }
        const float pre = (a0 + a1) + (a2 + a3) + b1t;
        hbuf[t] = pre / (1.0f + expf(-pre));
        __syncthreads();

        float s0 = 0.f, s1 = 0.f, s2 = 0.f, s3 = 0.f;
        const float4* h4 = (const float4*)(hbuf + c * 32);
        #pragma unroll
        for (int k = 0; k < 8; k += 2) {
            float4 ha = h4[k], hb = h4[k + 1];
            s0 = fmaf(w2r[k].x,     ha.x, s0); s1 = fmaf(w2r[k].y,     ha.y, s1);
            s2 = fmaf(w2r[k].z,     ha.z, s2); s3 = fmaf(w2r[k].w,     ha.w, s3);
            s0 = fmaf(w2r[k + 1].x, hb.x, s0); s1 = fmaf(w2r[k + 1].y, hb.y, s1);
            s2 = fmaf(w2r[k + 1].z, hb.z, s2); s3 = fmaf(w2r[k + 1].w, hb.w, s3);
        }
        float s = (s0 + s1) + (s2 + s3);
        s += __shfl_xor(s, 32);
        if ((t & 63) < 32) part[t >> 6][o] = s;
        __syncthreads();
        if (t < TOUT) {
            const float r = part[0][t] + part[1][t] + part[2][t] + part[3][t] + b2o;
            table[pair * TOUT + t] = r * 0.17677669529663687f;
        }
        __syncthreads();
    }
}

// ---------------------------------------------------------------------------
// Gather: dr/dc derived exactly from the flat index; only HBM traffic is the
// 128 MiB coalesced float4 output stream; table stays L2-resident.
__global__ __launch_bounds__(256) void gab_gather_kernel(
    const float* __restrict__ table,
    float4* __restrict__ out, int npairs)
{
    const int total = npairs * 8;
    const int stride = gridDim.x * blockDim.x;
    const float4* __restrict__ tbl4 = (const float4*)table;

    for (int idx = blockIdx.x * blockDim.x + threadIdx.x; idx < total; idx += stride) {
        const int p = idx >> 3;
        const int l = idx & 7;
        const int i = p >> 10;
        const int j = p & 1023;
        const int ir = (i >> 5) - (j >> 5) + (NOFF / 2);
        const int ic = (i & 31) - (j & 31) + (NOFF / 2);
        out[idx] = tbl4[(ir * NOFF + ic) * (TOUT / 4) + l];
    }
}

// ---------------------------------------------------------------------------
extern "C" void kernel_launch(void* const* d_in, const int* in_sizes, int n_in,
                              void* d_out, int out_size, void* d_ws, size_t ws_size,
                              hipStream_t stream) {
    // inputs: 0 seq_len 1 freqs(16) 2 W1(256*128) 3 b1(256) 4 W2(32*256)
    //         5 b2(32) 6 dr(S*S) 7 dc(S*S)
    const float* freqs = (const float*)d_in[1];
    const float* W1    = (const float*)d_in[2];
    const float* b1    = (const float*)d_in[3];
    const float* W2    = (const float*)d_in[4];
    const float* b2    = (const float*)d_in[5];
    float* out = (float*)d_out;

    const int npairs = in_sizes[6];                // S*S = 1024*1024

    // ws layout: [table 508 KB][feats ~2 MB]
    const size_t TBL_B   = (size_t)NPAIRS_TBL * TOUT * 4;    // 508,032 B
    const size_t FEATS_B = (size_t)NPAIRS_TBL * FIN * 4;     // 2,032,128 B
    float* table = (float*)d_ws;

    if (ws_size >= TBL_B + FEATS_B) {
        float* feats = (float*)((char*)d_ws + TBL_B);
        const int e_total = NPAIRS_TBL * FIN;
        gab_feats_kernel<<<(e_total + 255) / 256, 256, 0, stream>>>(freqs, feats);
        gab_mlp_kernel  <<<NBLK, 256, 0, stream>>>(feats, W1, b1, W2, b2, table);
    } else {
        gab_table_kernel<<<NBLK, 256, 0, stream>>>(freqs, W1, b1, W2, b2, table);
    }

    gab_gather_kernel<<<2048, 256, 0, stream>>>(table, (float4*)out, npairs);
}